// Round 4
// baseline (861.370 us; speedup 1.0000x reference)
//
#include <hip/hip_runtime.h>
#include <hip/hip_bf16.h>
#include <stdint.h>

#define Bn 16
#define Nn 8192
#define Dn 1024
#define Hn 256

typedef __attribute__((ext_vector_type(8))) short bf16x8;
typedef __attribute__((ext_vector_type(4))) float f32x4;

__device__ __forceinline__ short f2bf(float f) {
    __hip_bfloat16 h = __float2bfloat16(f);   // hw RNE cvt
    return *reinterpret_cast<short*>(&h);
}

// fast tanh: 1 - 2/(1+e^{2x}); exact at +/-inf
__device__ __forceinline__ float tanh_fast(float x) {
    float e = __expf(2.0f * x);
    return 1.0f - __fdividef(2.0f, 1.0f + e);
}

// ---------------- W1 fp32 -> bf16, panel-major + XOR-swizzled ----------------
// 16 panels (k-panel p = k/64), each 256 rows x 64 k bf16 = 32768 B.
// 16B chunk (h, c8) stored at byte h*128 + ((c8 ^ (h&7))<<4). k_scores stages a
// panel LINEARLY via global_load_lds; ds_read applies the same XOR -> conflict-free.
__global__ __launch_bounds__(256) void k_cvt_w1(const float* __restrict__ W1,
                                                short* __restrict__ w1s) {
    int i   = blockIdx.x * 256 + threadIdx.x;
    int h   = i >> 7;
    int kk8 = i & 127;
    int p   = kk8 >> 3;
    int c8  = kk8 & 7;
    const float* src = W1 + h * Dn + kk8 * 8;
    bf16x8 pk;
#pragma unroll
    for (int j = 0; j < 8; ++j) pk[j] = f2bf(src[j]);
    char* dst = (char*)w1s + p * 32768 + h * 128 + ((c8 ^ (h & 7)) << 4);
    *(bf16x8*)dst = pk;
}

// ---------------- fused: scores GEMM -> local softmax -> weighted partial ----
// Block: 64 rows x 256 cols (all H), 4 waves, wave tile 64x64, BK=64, 256 thr.
// LDS 42 KB -> 3 blocks/CU. Epilogue re-reads the block's own 256 KB X chunk;
// concurrent working set 768 x 256 KB = 192 MB < 256 MB L3 -> L3 hits.
#define XSTR 72

__global__ __launch_bounds__(256) void k_scores(const float* __restrict__ X,
                                                const short* __restrict__ w1s,
                                                const float* __restrict__ W2,
                                                float2* __restrict__ ml,
                                                float* __restrict__ partial) {
    __shared__ short xa[64 * XSTR];    // 9216 B
    __shared__ short wb[256 * 64];     // 32768 B (swizzled panel image)
    __shared__ float sc[64];
    __shared__ float mred;

    const int tid  = threadIdx.x;
    const int wave = tid >> 6;         // 0..3 = H-quarter
    const int lane = tid & 63;
    const int quad = lane >> 4;
    const int l16  = lane & 15;

    const long row0 = (long)blockIdx.x * 64;
    const float* xbase = X + row0 * Dn;

    // X staging: thread t -> row t>>2 (0..63), k-offset (t&3)*16 (16 fp32)
    const int srow = tid >> 2;
    const int sk   = (tid & 3) << 4;

    f32x4 acc[4][4];
#pragma unroll
    for (int mi = 0; mi < 4; ++mi)
#pragma unroll
        for (int ni = 0; ni < 4; ++ni)
            acc[mi][ni] = (f32x4){0.f, 0.f, 0.f, 0.f};

    float w2v[4];
#pragma unroll
    for (int ni = 0; ni < 4; ++ni) w2v[ni] = W2[wave * 64 + ni * 16 + l16];

    for (int k0 = 0; k0 < Dn; k0 += 64) {
        // ---- stage X tile (64x64) fp32 -> bf16 in registers ----
        {
            const float* src = xbase + (long)srow * Dn + k0 + sk;
            float4 f0 = *(const float4*)(src);
            float4 f1 = *(const float4*)(src + 4);
            float4 f2 = *(const float4*)(src + 8);
            float4 f3 = *(const float4*)(src + 12);
            bf16x8 p0, p1;
            p0[0] = f2bf(f0.x); p0[1] = f2bf(f0.y); p0[2] = f2bf(f0.z); p0[3] = f2bf(f0.w);
            p0[4] = f2bf(f1.x); p0[5] = f2bf(f1.y); p0[6] = f2bf(f1.z); p0[7] = f2bf(f1.w);
            p1[0] = f2bf(f2.x); p1[1] = f2bf(f2.y); p1[2] = f2bf(f2.z); p1[3] = f2bf(f2.w);
            p1[4] = f2bf(f3.x); p1[5] = f2bf(f3.y); p1[6] = f2bf(f3.z); p1[7] = f2bf(f3.w);
            *(bf16x8*)(&xa[srow * XSTR + sk]) = p0;
            *(bf16x8*)(&xa[srow * XSTR + sk + 8]) = p1;
        }
        // ---- stage W1 panel (256x64 bf16 = 32 KB) via global_load_lds x8 ----
        {
            const char* wsrc = (const char*)w1s + ((long)k0 << 9);
            char* wdst = (char*)wb;
#pragma unroll
            for (int j = 0; j < 8; ++j)
                __builtin_amdgcn_global_load_lds(
                    (const __attribute__((address_space(1))) unsigned int*)(wsrc + j * 4096 + tid * 16),
                    (__attribute__((address_space(3))) unsigned int*)(wdst + j * 4096 + tid * 16),
                    16, 0, 0);
        }
        __syncthreads();

#pragma unroll
        for (int ks = 0; ks < 2; ++ks) {
            bf16x8 af[4], bq[4];
#pragma unroll
            for (int mi = 0; mi < 4; ++mi)
                af[mi] = *(const bf16x8*)(&xa[(mi * 16 + l16) * XSTR + ks * 32 + quad * 8]);
#pragma unroll
            for (int ni = 0; ni < 4; ++ni) {
                int rw    = wave * 64 + ni * 16 + l16;
                int byteo = (rw * 128 + ks * 64 + quad * 16) ^ ((rw & 7) << 4);
                bq[ni] = *(const bf16x8*)((const char*)wb + byteo);
            }
#pragma unroll
            for (int mi = 0; mi < 4; ++mi)
#pragma unroll
                for (int ni = 0; ni < 4; ++ni)
                    acc[mi][ni] = __builtin_amdgcn_mfma_f32_16x16x32_bf16(af[mi], bq[ni], acc[mi][ni], 0, 0, 0);
        }
        __syncthreads();
    }

    // ---- epilogue: sc[row] = sum_h W2[h]*tanh(C[row,h]) ----
    // C/D layout: col = l16 (+ni*16 + wave*64), row = quad*4 + r (+mi*16)
    if (tid < 64) sc[tid] = 0.f;
    __syncthreads();

#pragma unroll
    for (int mi = 0; mi < 4; ++mi) {
#pragma unroll
        for (int r = 0; r < 4; ++r) {
            float p = 0.f;
#pragma unroll
            for (int ni = 0; ni < 4; ++ni)
                p += w2v[ni] * tanh_fast(acc[mi][ni][r]);
            p += __shfl_xor(p, 1);
            p += __shfl_xor(p, 2);
            p += __shfl_xor(p, 4);
            p += __shfl_xor(p, 8);
            if (l16 == 0) atomicAdd(&sc[mi * 16 + quad * 4 + r], p);
        }
    }
    __syncthreads();

    // ---- chunk-local softmax: m_c, p_n = exp(s - m_c), l_c ----
    if (wave == 0) {
        float v = sc[lane];
#pragma unroll
        for (int o = 32; o >= 1; o >>= 1) v = fmaxf(v, __shfl_xor(v, o));
        if (lane == 0) mred = v;
    }
    __syncthreads();
    const float m_c = mred;
    if (tid < 64) sc[tid] = __expf(sc[tid] - m_c);
    __syncthreads();
    if (wave == 0) {
        float s = sc[lane];
#pragma unroll
        for (int o = 32; o >= 1; o >>= 1) s += __shfl_xor(s, o);
        if (lane == 0) ml[blockIdx.x] = make_float2(m_c, s);
    }

    // ---- weighted partial: partial[chunk][d] = sum_n p_n * X[row0+n, d] ----
    // Thread t owns d = 4t..4t+3 (float4); each n-step reads the full 4 KB row.
    {
        const float* xw = X + row0 * Dn + tid * 4;
        float4 e = make_float4(0.f, 0.f, 0.f, 0.f);
        float4 o = make_float4(0.f, 0.f, 0.f, 0.f);
#pragma unroll 4
        for (int n = 0; n < 64; n += 2) {
            float a0 = sc[n];
            float a1 = sc[n + 1];
            float4 x0 = *(const float4*)(xw + (long)n * Dn);
            float4 x1 = *(const float4*)(xw + (long)(n + 1) * Dn);
            e.x += a0 * x0.x; e.y += a0 * x0.y; e.z += a0 * x0.z; e.w += a0 * x0.w;
            o.x += a1 * x1.x; o.y += a1 * x1.y; o.z += a1 * x1.z; o.w += a1 * x1.w;
        }
        float4 r = make_float4(e.x + o.x, e.y + o.y, e.z + o.z, e.w + o.w);
        *(float4*)(partial + (long)blockIdx.x * Dn + tid * 4) = r;
    }
}

// ---------------- combine: out[b,d] = sum_c e^{m_c-M} partial[c][d] / L ------
// 128 chunks of 64 rows per batch.
__global__ __launch_bounds__(1024) void k_combine(const float* __restrict__ partial,
                                                  const float2* __restrict__ ml,
                                                  float* __restrict__ out) {
    const int b   = blockIdx.x;
    const int tid = threadIdx.x;
    __shared__ float ms[128];
    __shared__ float ls[128];
    __shared__ float es[128];

    if (tid < 128) {
        float2 v = ml[b * 128 + tid];
        ms[tid] = v.x;
        ls[tid] = v.y;
    }
    __syncthreads();

    float M = -1e30f;
#pragma unroll
    for (int c = 0; c < 128; ++c) M = fmaxf(M, ms[c]);   // uniform LDS broadcast
    if (tid < 128) es[tid] = __expf(ms[tid] - M);
    __syncthreads();

    float L = 0.f;
#pragma unroll
    for (int c = 0; c < 128; ++c) L += es[c] * ls[c];

    const float* p = partial + (long)b * 128 * Dn + tid;
    float acc = 0.f;
#pragma unroll 8
    for (int c = 0; c < 128; ++c) acc += es[c] * p[(long)c * Dn];

    out[b * Dn + tid] = acc / L;
}

extern "C" void kernel_launch(void* const* d_in, const int* in_sizes, int n_in,
                              void* d_out, int out_size, void* d_ws, size_t ws_size,
                              hipStream_t stream) {
    (void)in_sizes; (void)n_in; (void)ws_size; (void)out_size;
    const float* X  = (const float*)d_in[0];
    const float* W1 = (const float*)d_in[1];
    const float* W2 = (const float*)d_in[2];
    float* out = (float*)d_out;

    char* ws = (char*)d_ws;
    short*  w1s     = (short*)ws;                    // 512 KB (swizzled panels)
    float2* ml      = (float2*)(ws + (1 << 19));     // 16 KB (m_c, l_c per chunk)
    float*  partial = (float*)(ws + (1 << 20));      // 8 MB  [2048 chunks][1024 d]

    k_cvt_w1<<<(Hn * Dn) / 8 / 256, 256, 0, stream>>>(W1, w1s);
    k_scores<<<(Bn * Nn) / 64, 256, 0, stream>>>(X, w1s, W2, ml, partial);
    k_combine<<<Bn, 1024, 0, stream>>>(partial, ml, out);
}

// Round 6
// 794.178 us; speedup vs baseline: 1.0846x; 1.0846x over previous
//
#include <hip/hip_runtime.h>
#include <hip/hip_bf16.h>
#include <stdint.h>

#define Bn 16
#define Nn 8192
#define Dn 1024
#define Hn 256

typedef __attribute__((ext_vector_type(8))) short bf16x8;
typedef __attribute__((ext_vector_type(4))) float f32x4;

__device__ __forceinline__ short f2bf(float f) {
    __hip_bfloat16 h = __float2bfloat16(f);   // hw RNE cvt (pairs into v_cvt_pk_bf16_f32)
    return *reinterpret_cast<short*>(&h);
}

// fast tanh: 1 - 2/(1+e^{2x}); exact at +/-inf
__device__ __forceinline__ float tanh_fast(float x) {
    float e = __expf(2.0f * x);
    return 1.0f - __fdividef(2.0f, 1.0f + e);
}

// ---------------- W1 fp32 -> bf16, panel-major + XOR-swizzled ----------------
// 16 panels (k-panel p = k/64), each 256 rows x 64 k bf16 = 32768 B.
// 16B chunk (h, c8) stored at byte h*128 + ((c8 ^ (h&7))<<4). k_scores stages a
// panel LINEARLY via global_load_lds; ds_read applies the same XOR -> conflict-free.
__global__ __launch_bounds__(256) void k_cvt_w1(const float* __restrict__ W1,
                                                short* __restrict__ w1s) {
    int i   = blockIdx.x * 256 + threadIdx.x;
    int h   = i >> 7;
    int kk8 = i & 127;
    int p   = kk8 >> 3;
    int c8  = kk8 & 7;
    const float* src = W1 + h * Dn + kk8 * 8;
    bf16x8 pk;
#pragma unroll
    for (int j = 0; j < 8; ++j) pk[j] = f2bf(src[j]);
    char* dst = (char*)w1s + p * 32768 + h * 128 + ((c8 ^ (h & 7)) << 4);
    *(bf16x8*)dst = pk;
}

// ---------------- scores GEMM: X[131072,1024] x W1^T -> tanh -> dot W2 --------
// Block: 64 rows x 256 cols (all H), 4 waves, wave tile 64x64, BK=64, 256 thr.
// BOTH operands staged via global_load_lds (m193: +67% vs reg-staging).
// X staged as fp32 [64][64] with chunk-XOR swizzle applied on the per-lane
// GLOBAL source address (LDS dest stays linear); bf16 cvt at frag read.
__global__ __launch_bounds__(256) void k_scores(const float* __restrict__ X,
                                                const short* __restrict__ w1s,
                                                const float* __restrict__ W2,
                                                float* __restrict__ scores) {
    __shared__ float xa[64 * 64];      // 16384 B (swizzled image: chunk c -> c^(r&15))
    __shared__ short wb[256 * 64];     // 32768 B (swizzled panel image)
    __shared__ float sc[64];

    const int tid  = threadIdx.x;
    const int wave = tid >> 6;         // 0..3 = H-quarter
    const int lane = tid & 63;
    const int quad = lane >> 4;
    const int l16  = lane & 15;

    const long row0 = (long)blockIdx.x * 64;
    const float* xbase = X + row0 * Dn;

    // X staging: LDS linear byte o = j*4096 + tid*16  ->  row r = (tid>>4)+j*16,
    // physical chunk pc = tid&15, logical chunk c = pc ^ (r&15) = (tid&15)^(tid>>4)
    const int r0 = tid >> 4;                 // 0..15, j-invariant low bits of row
    const int cs = (tid & 15) ^ r0;          // logical 16B chunk (j-invariant)

    f32x4 acc[4][4];
#pragma unroll
    for (int mi = 0; mi < 4; ++mi)
#pragma unroll
        for (int ni = 0; ni < 4; ++ni)
            acc[mi][ni] = (f32x4){0.f, 0.f, 0.f, 0.f};

    float w2v[4];
#pragma unroll
    for (int ni = 0; ni < 4; ++ni) w2v[ni] = W2[wave * 64 + ni * 16 + l16];

    for (int k0 = 0; k0 < Dn; k0 += 64) {
        // ---- stage X tile (64x64 fp32 = 16 KB) via global_load_lds x4 ----
        {
            const float* xsrc = xbase + (long)r0 * Dn + k0 + cs * 4;
            char* xdst = (char*)xa;
#pragma unroll
            for (int j = 0; j < 4; ++j)
                __builtin_amdgcn_global_load_lds(
                    (const __attribute__((address_space(1))) unsigned int*)(xsrc + (long)(j * 16) * Dn),
                    (__attribute__((address_space(3))) unsigned int*)(xdst + j * 4096 + tid * 16),
                    16, 0, 0);
        }
        // ---- stage W1 panel (256x64 bf16 = 32 KB) via global_load_lds x8 ----
        {
            const char* wsrc = (const char*)w1s + ((long)k0 << 9);
            char* wdst = (char*)wb;
#pragma unroll
            for (int j = 0; j < 8; ++j)
                __builtin_amdgcn_global_load_lds(
                    (const __attribute__((address_space(1))) unsigned int*)(wsrc + j * 4096 + tid * 16),
                    (__attribute__((address_space(3))) unsigned int*)(wdst + j * 4096 + tid * 16),
                    16, 0, 0);
        }
        __syncthreads();

#pragma unroll
        for (int ks = 0; ks < 2; ++ks) {
            bf16x8 af[4], bq[4];
#pragma unroll
            for (int mi = 0; mi < 4; ++mi) {
                // A frag: row = mi*16+l16, k = ks*32+quad*8 .. +7
                // logical chunks {ks*8+quad*2, +1}, physical = logical ^ (row&15) = ^l16
                int arow = mi * 16 + l16;
                int ach  = ks * 8 + quad * 2;
                const char* xab = (const char*)xa + arow * 256;
                float4 a0 = *(const float4*)(xab + ((ach ^ l16) << 4));
                float4 a1 = *(const float4*)(xab + (((ach + 1) ^ l16) << 4));
                bf16x8 v;
                v[0] = f2bf(a0.x); v[1] = f2bf(a0.y); v[2] = f2bf(a0.z); v[3] = f2bf(a0.w);
                v[4] = f2bf(a1.x); v[5] = f2bf(a1.y); v[6] = f2bf(a1.z); v[7] = f2bf(a1.w);
                af[mi] = v;
            }
#pragma unroll
            for (int ni = 0; ni < 4; ++ni) {
                int rw    = wave * 64 + ni * 16 + l16;
                int byteo = (rw * 128 + ks * 64 + quad * 16) ^ ((rw & 7) << 4);
                bq[ni] = *(const bf16x8*)((const char*)wb + byteo);
            }
#pragma unroll
            for (int mi = 0; mi < 4; ++mi)
#pragma unroll
                for (int ni = 0; ni < 4; ++ni)
                    acc[mi][ni] = __builtin_amdgcn_mfma_f32_16x16x32_bf16(af[mi], bq[ni], acc[mi][ni], 0, 0, 0);
        }
        __syncthreads();
    }

    // ---- epilogue: sc[row] = sum_h W2[h]*tanh(C[row,h]) ----
    // C/D layout: col = l16 (+ni*16 + wave*64), row = quad*4 + r (+mi*16)
    if (tid < 64) sc[tid] = 0.f;
    __syncthreads();

#pragma unroll
    for (int mi = 0; mi < 4; ++mi) {
#pragma unroll
        for (int r = 0; r < 4; ++r) {
            float p = 0.f;
#pragma unroll
            for (int ni = 0; ni < 4; ++ni)
                p += w2v[ni] * tanh_fast(acc[mi][ni][r]);
            p += __shfl_xor(p, 1);
            p += __shfl_xor(p, 2);
            p += __shfl_xor(p, 4);
            p += __shfl_xor(p, 8);
            if (l16 == 0) atomicAdd(&sc[mi * 16 + quad * 4 + r], p);
        }
    }
    __syncthreads();
    if (tid < 64) scores[row0 + tid] = sc[tid];
}

// ---------------- softmax over N per batch: 1024 thr, 1 read pass ----------------
__global__ __launch_bounds__(1024) void k_softmax(const float* __restrict__ scores,
                                                  float* __restrict__ attn) {
    const int b   = blockIdx.x;
    const int tid = threadIdx.x;
    const float* s = scores + b * Nn;
    __shared__ float redm[16];
    __shared__ float reds[16];

    float4 v0 = ((const float4*)s)[tid * 2];
    float4 v1 = ((const float4*)s)[tid * 2 + 1];

    float m = fmaxf(fmaxf(fmaxf(v0.x, v0.y), fmaxf(v0.z, v0.w)),
                    fmaxf(fmaxf(v1.x, v1.y), fmaxf(v1.z, v1.w)));
#pragma unroll
    for (int o = 32; o >= 1; o >>= 1) m = fmaxf(m, __shfl_xor(m, o));
    if ((tid & 63) == 0) redm[tid >> 6] = m;
    __syncthreads();
    m = redm[0];
#pragma unroll
    for (int i = 1; i < 16; ++i) m = fmaxf(m, redm[i]);

    float e[8];
    e[0] = __expf(v0.x - m); e[1] = __expf(v0.y - m);
    e[2] = __expf(v0.z - m); e[3] = __expf(v0.w - m);
    e[4] = __expf(v1.x - m); e[5] = __expf(v1.y - m);
    e[6] = __expf(v1.z - m); e[7] = __expf(v1.w - m);
    float sum = ((e[0] + e[1]) + (e[2] + e[3])) + ((e[4] + e[5]) + (e[6] + e[7]));
#pragma unroll
    for (int o = 32; o >= 1; o >>= 1) sum += __shfl_xor(sum, o);
    if ((tid & 63) == 0) reds[tid >> 6] = sum;
    __syncthreads();
    float tot = 0.f;
#pragma unroll
    for (int i = 0; i < 16; ++i) tot += reds[i];
    const float inv = 1.0f / tot;

    float* a = attn + b * Nn;
    ((float4*)a)[tid * 2]     = make_float4(e[0] * inv, e[1] * inv, e[2] * inv, e[3] * inv);
    ((float4*)a)[tid * 2 + 1] = make_float4(e[4] * inv, e[5] * inv, e[6] * inv, e[7] * inv);
}

// ---------------- pass 2: partial[b*32+c][d] = sum_{n in chunk} attn*X --------
// 256-row chunks, 512 blocks, thread t owns d = 4t..4t+3 (float4, coalesced).
__global__ __launch_bounds__(256) void k_wsum(const float* __restrict__ X,
                                              const float* __restrict__ attn,
                                              float* __restrict__ part) {
    const int b   = blockIdx.y;
    const int c   = blockIdx.x;
    const int tid = threadIdx.x;
    __shared__ float a_s[256];
    a_s[tid] = attn[b * Nn + c * 256 + tid];
    __syncthreads();

    const float* xp = X + ((long)b * Nn + (long)c * 256) * Dn + tid * 4;
    float4 e = make_float4(0.f, 0.f, 0.f, 0.f);
    float4 o = make_float4(0.f, 0.f, 0.f, 0.f);
#pragma unroll 4
    for (int n = 0; n < 256; n += 2) {
        float4 x0 = *(const float4*)(xp + (long)n * Dn);
        float4 x1 = *(const float4*)(xp + (long)(n + 1) * Dn);
        float a0 = a_s[n];
        float a1 = a_s[n + 1];
        e.x += a0 * x0.x; e.y += a0 * x0.y; e.z += a0 * x0.z; e.w += a0 * x0.w;
        o.x += a1 * x1.x; o.y += a1 * x1.y; o.z += a1 * x1.z; o.w += a1 * x1.w;
    }
    float4 r = make_float4(e.x + o.x, e.y + o.y, e.z + o.z, e.w + o.w);
    *(float4*)(part + (long)(b * 32 + c) * Dn + tid * 4) = r;
}

// out[b][d] = sum_c part[b*32+c][d]   (2 MB read, trivial)
__global__ __launch_bounds__(256) void k_reduce(const float* __restrict__ part,
                                                float* __restrict__ out) {
    int i = blockIdx.x * 256 + threadIdx.x;   // 0..16383
    int b = i >> 10;
    int d = i & 1023;
    const float* p = part + (long)b * 32 * Dn + d;
    float s = 0.f;
#pragma unroll 8
    for (int c = 0; c < 32; ++c) s += p[c * Dn];
    out[i] = s;
}

extern "C" void kernel_launch(void* const* d_in, const int* in_sizes, int n_in,
                              void* d_out, int out_size, void* d_ws, size_t ws_size,
                              hipStream_t stream) {
    (void)in_sizes; (void)n_in; (void)ws_size; (void)out_size;
    const float* X  = (const float*)d_in[0];
    const float* W1 = (const float*)d_in[1];
    const float* W2 = (const float*)d_in[2];
    float* out = (float*)d_out;

    char* ws = (char*)d_ws;
    short* w1s    = (short*)ws;                      // 512 KB (swizzled panels)
    float* scores = (float*)(ws + (1 << 19));        // 512 KB
    float* attn   = (float*)(ws + (2 << 19));        // 512 KB
    float* part   = (float*)(ws + (3 << 19));        // 2 MB  [512 chunks][1024 d]

    k_cvt_w1<<<(Hn * Dn) / 8 / 256, 256, 0, stream>>>(W1, w1s);
    k_scores<<<(Bn * Nn) / 64, 256, 0, stream>>>(X, w1s, W2, scores);
    k_softmax<<<Bn, 1024, 0, stream>>>(scores, attn);
    dim3 g(32, Bn);
    k_wsum<<<g, 256, 0, stream>>>(X, attn, part);
    k_reduce<<<64, 256, 0, stream>>>(part, out);
}